// Round 19
// baseline (67.172 us; speedup 1.0000x reference)
//
#include <hip/hip_runtime.h>

// Chamfer loss via 32x32x16 MFMA — SINGLE fused kernel.
// X, Y f32 [8, 3, 4096] -> scalar mean of (d1+d2)/2.
// dir 0: queries = X, targets = Y; dir 1: queries = Y, targets = X.
//
// d'(q,t) = ||t||^2 - 2 q.t with hi/lo-split bf16 (verified R6-R18):
//   k0..11: per coord: Q=(qh,qh,ql,ql) (qh+ql ~= -2q_c), T=(th,tl,th,tl)
//   k12,13: Q=(1,1), T=(rt_hi,rt_lo); k14,15 = 0.  K=16 exact.
// Swapped operands (R12): D = mfma(A=targets, B=queries) -> col = query =
// lane-local; 16 regs = 16 targets.
//
// R19 vs R18:
//   1) reduce kernel FUSED into main via last-block counter handshake
//      (R5/R8-proven; all-thread __threadfence release, poison-proof
//      (old&255)==255 fire test) -> one graph node, no gap.
//   2) split accumulators runA/runB (dA->runA, dB->runB, merged in
//      epilogue): same fmin count, 2x shallower run dependency chains.
// Geometry (R18): grid 256 = 16 pairs x 4 qgroups x 4 slices, 512 thr
// (8 waves, 2/SIMD), 32 KB LDS, half-swap swizzle.

typedef __attribute__((ext_vector_type(8))) short short8;
typedef __attribute__((ext_vector_type(16))) float f32x16;
typedef __attribute__((ext_vector_type(4))) unsigned uint4v;

constexpr int NPTS  = 4096;
constexpr int NB    = 8;
constexpr int NQ    = 2 * NB * NPTS;      // 65536 query slots
constexpr int TSN   = 4;                  // target slices
constexpr int TGT   = 1024;               // targets per slice
constexpr int TILES = TGT / 32;           // 32
constexpr int TPB   = 512;                // 8 waves per block
constexpr int GRID_MAIN  = 16 * 4 * TSN;  // 256 = 1 block/CU

__device__ inline unsigned short f2bf(float x) {      // round-to-nearest-even
    unsigned u = __float_as_uint(x);
    unsigned r = u + 0x7fff + ((u >> 16) & 1);
    return (unsigned short)(r >> 16);
}
__device__ inline float bf2f(unsigned short h) {
    return __uint_as_float(((unsigned)h) << 16);
}
__device__ inline unsigned pack2(unsigned short a, unsigned short b) {
    return (unsigned)a | ((unsigned)b << 16);
}

__global__ __launch_bounds__(TPB, 2) void chamfer_fused(
    const float* __restrict__ X, const float* __restrict__ Y,
    float* __restrict__ minq, unsigned* __restrict__ counter,
    float* __restrict__ out)
{
    __shared__ char  BL[TGT * 32];        // 32 KB
    __shared__ float wsum[8];
    __shared__ int   fireFlag;

    const int bid  = blockIdx.x;
    const int ts   = bid & 3;
    const int qg   = (bid >> 2) & 3;
    const int pair = bid >> 4;            // dir*8 + b
    const int dir  = pair >> 3, b = pair & 7;
    const int tid  = threadIdx.x;
    const int lane = tid & 63, wv = tid >> 6;          // wv: 0..7
    const int c    = lane & 31, h = lane >> 5;

    const float* __restrict__ Qraw = (dir ? Y : X) + b * 3 * NPTS;
    const float* __restrict__ Traw = (dir ? X : Y) + b * 3 * NPTS;

    // ---- pack this block's 1024-target slice into LDS (2 pts/thread) ----
    #pragma unroll
    for (int k = 0; k < 2; ++k) {
        const int p = k * TPB + tid;                     // 0..1023
        const int i = ts * TGT + p;
        float tx = Traw[i], ty = Traw[NPTS + i], tz = Traw[2 * NPTS + i];
        float r  = fmaf(tx, tx, fmaf(ty, ty, tz * tz));
        unsigned short hx = f2bf(tx), lx = f2bf(tx - bf2f(hx));
        unsigned short hy = f2bf(ty), ly = f2bf(ty - bf2f(hy));
        unsigned short hz = f2bf(tz), lz = f2bf(tz - bf2f(hz));
        unsigned short hr = f2bf(r),  lr = f2bf(r  - bf2f(hr));
        unsigned w0 = pack2(hx, lx), w2 = pack2(hy, ly), w4 = pack2(hz, lz);
        unsigned w6 = pack2(hr, lr);
        uint4v lo = {w0, w0, w2, w2};                    // k0..7
        uint4v hi = {w4, w4, w6, 0u};                    // k8..15
        const int sw = (p >> 2) & 1;                     // half-swap swizzle
        *(uint4v*)(BL + p * 32 + ((0 ^ sw) << 4)) = lo;
        *(uint4v*)(BL + p * 32 + ((1 ^ sw) << 4)) = hi;
    }

    // ---- B fragments (queries): 4 strips of 32 per wave ----
    union Frag { uint4v u; short8 s; };
    Frag qfr[4];
    float ra[4];
    #pragma unroll
    for (int s = 0; s < 4; ++s) {
        const int q = qg * 1024 + wv * 128 + s * 32 + c;
        float qx = Qraw[q], qy = Qraw[NPTS + q], qz = Qraw[2 * NPTS + q];
        ra[s] = fmaf(qx, qx, fmaf(qy, qy, qz * qz));
        float mx = -2.f * qx, my = -2.f * qy, mz = -2.f * qz;
        unsigned short hx = f2bf(mx), lx = f2bf(mx - bf2f(hx));
        unsigned short hy = f2bf(my), ly = f2bf(my - bf2f(hy));
        unsigned short hz = f2bf(mz), lz = f2bf(mz - bf2f(hz));
        uint4v f0 = {pack2(hx, hx), pack2(lx, lx), pack2(hy, hy), pack2(ly, ly)};
        uint4v f1 = {pack2(hz, hz), pack2(lz, lz), 0x3F803F80u, 0u};
        Frag f; f.u = h ? f1 : f0;
        qfr[s] = f;
    }

    __syncthreads();                                     // targets staged

    // ---- main loop: 32 tiles, 2/iter; SPLIT accumulators (2 chains) ----
    f32x16 runA[4], runB[4];
    #pragma unroll
    for (int s = 0; s < 4; ++s)
        #pragma unroll
        for (int i = 0; i < 16; ++i) { runA[s][i] = 3.4e38f; runB[s][i] = 3.4e38f; }
    f32x16 zacc;
    #pragma unroll
    for (int i = 0; i < 16; ++i) zacc[i] = 0.f;

    // A lane map (targets): row = lane&31, k = h*8+j; swizzled read.
    const char* base = BL + c * 32 + ((h ^ ((c >> 2) & 1)) << 4);

    short8 tf0 = *(const short8*)(base);
    short8 tf1 = *(const short8*)(base + 1024);
    for (int t = 0; t < TILES; t += 2) {
        const int t2 = (t + 2) & (TILES - 1);            // wrap: dummy tail
        const int t3 = (t + 3) & (TILES - 1);
        short8 nf0 = *(const short8*)(base + t2 * 1024);
        short8 nf1 = *(const short8*)(base + t3 * 1024);
        #pragma unroll
        for (int s = 0; s < 4; ++s) {
            // D[m=target][n=query]: col (lane) = query, regs = 16 targets.
            f32x16 dA = __builtin_amdgcn_mfma_f32_32x32x16_bf16(tf0, qfr[s].s, zacc, 0, 0, 0);
            f32x16 dB = __builtin_amdgcn_mfma_f32_32x32x16_bf16(tf1, qfr[s].s, zacc, 0, 0, 0);
            #pragma unroll
            for (int i = 0; i < 16; ++i) {
                runA[s][i] = fminf(runA[s][i], dA[i]);   // chain A
                runB[s][i] = fminf(runB[s][i], dB[i]);   // chain B (indep)
            }
        }
        tf0 = nf0; tf1 = nf1;
    }

    // ---- epilogue: merge chains, fmin tree, h-half swap, + ra, store ----
    #pragma unroll
    for (int s = 0; s < 4; ++s) {
        float v0 = fminf(runA[s][0],  runB[s][0]),  v1 = fminf(runA[s][1],  runB[s][1]);
        float v2 = fminf(runA[s][2],  runB[s][2]),  v3 = fminf(runA[s][3],  runB[s][3]);
        float v4 = fminf(runA[s][4],  runB[s][4]),  v5 = fminf(runA[s][5],  runB[s][5]);
        float v6 = fminf(runA[s][6],  runB[s][6]),  v7 = fminf(runA[s][7],  runB[s][7]);
        float v8 = fminf(runA[s][8],  runB[s][8]),  v9 = fminf(runA[s][9],  runB[s][9]);
        float va = fminf(runA[s][10], runB[s][10]), vb = fminf(runA[s][11], runB[s][11]);
        float vc = fminf(runA[s][12], runB[s][12]), vd = fminf(runA[s][13], runB[s][13]);
        float ve = fminf(runA[s][14], runB[s][14]), vf = fminf(runA[s][15], runB[s][15]);
        float m0 = fminf(fminf(v0, v1), fminf(v2, v3));
        float m1 = fminf(fminf(v4, v5), fminf(v6, v7));
        float m2 = fminf(fminf(v8, v9), fminf(va, vb));
        float m3 = fminf(fminf(vc, vd), fminf(ve, vf));
        float m  = fminf(fminf(m0, m1), fminf(m2, m3));
        m = fminf(m, __shfl_xor(m, 32));                 // combine h halves
        m += ra[s];                                      // ra + slice-min
        if (h == 0)
            minq[(size_t)ts * NQ + pair * 4096 + qg * 1024 + wv * 128 + s * 32 + c] = m;
    }

    // ---- last-block handshake (poison-proof) + fused final reduction ----
    __threadfence();                      // release own minq stores (all thr)
    __syncthreads();                      // all fences done before the atomic
    if (tid == 0) {
        unsigned old = atomicAdd(counter, 1u);           // device-scope
        fireFlag = ((old & 255u) == 255u);               // fires once/call
    }
    __syncthreads();

    if (fireFlag) {                        // block-uniform branch
        __threadfence();                   // acquire all blocks' minq
        const float4* mq4 = (const float4*)minq;
        float acc = 0.0f;
        #pragma unroll
        for (int k = 0; k < NQ / 4 / TPB; ++k) {         // 32 slots/thread
            const int idx = k * TPB + tid;
            float4 m = mq4[idx];
            #pragma unroll
            for (int s = 1; s < TSN; ++s) {
                float4 v = mq4[s * (NQ / 4) + idx];
                m.x = fminf(m.x, v.x); m.y = fminf(m.y, v.y);
                m.z = fminf(m.z, v.z); m.w = fminf(m.w, v.w);
            }
            acc += (m.x + m.y) + (m.z + m.w);
        }
        #pragma unroll
        for (int off = 1; off < 64; off <<= 1) acc += __shfl_xor(acc, off);
        if (lane == 0) wsum[wv] = acc;
        __syncthreads();
        if (tid == 0) {
            float tsum = ((wsum[0] + wsum[1]) + (wsum[2] + wsum[3]))
                       + ((wsum[4] + wsum[5]) + (wsum[6] + wsum[7]));
            out[0] = tsum * (1.0f / 65536.0f);           // mean of (d1+d2)/2
        }
    }
}

extern "C" void kernel_launch(void* const* d_in, const int* in_sizes, int n_in,
                              void* d_out, int out_size, void* d_ws, size_t ws_size,
                              hipStream_t stream) {
    const float* X = (const float*)d_in[0];
    const float* Y = (const float*)d_in[1];

    float*    minq    = (float*)d_ws;                        // 4*65536 f32 = 1 MB
    unsigned* counter = (unsigned*)(minq + (size_t)TSN * NQ);// 1 u32 (any init OK)
    float*    out     = (float*)d_out;

    chamfer_fused<<<GRID_MAIN, TPB, 0, stream>>>(X, Y, minq, counter, out);
}

// Round 20
// 62.617 us; speedup vs baseline: 1.0727x; 1.0727x over previous
//
#include <hip/hip_runtime.h>

// Chamfer loss via 32x32x16 MFMA — single fused kernel.
// X, Y f32 [8, 3, 4096] -> scalar mean of (d1+d2)/2.
// dir 0: queries = X, targets = Y; dir 1: queries = Y, targets = X.
//
// d'(q,t) = ||t||^2 - 2 q.t with hi/lo-split bf16 (verified R6-R19):
//   k0..11: per coord: Q=(qh,qh,ql,ql) (qh+ql ~= -2q_c), T=(th,tl,th,tl)
//   k12,13: Q=(1,1), T=(rt_hi,rt_lo); k14,15 = 0.  K=16 exact.
// Swapped operands (R12): D = mfma(A=targets, B=queries) -> col = query =
// lane-local; 16 regs = 16 targets.
//
// R20 = R18's EXACT loop (single run[4] accumulator — R19's split chains
// spilled: VGPR=100 < 128 live accums, MfmaUtil 4.6%, 67us) + R19's fused
// last-block reduce (handshake proven correct there). Accumulator set is
// at the register cliff: do not grow it (R10, R19 both died this way).
// Geometry (R18): grid 256 = 16 pairs x 4 qgroups x 4 slices, 512 thr
// (8 waves, 2/SIMD), 32 KB LDS, half-swap swizzle.

typedef __attribute__((ext_vector_type(8))) short short8;
typedef __attribute__((ext_vector_type(16))) float f32x16;
typedef __attribute__((ext_vector_type(4))) unsigned uint4v;

constexpr int NPTS  = 4096;
constexpr int NB    = 8;
constexpr int NQ    = 2 * NB * NPTS;      // 65536 query slots
constexpr int TSN   = 4;                  // target slices
constexpr int TGT   = 1024;               // targets per slice
constexpr int TILES = TGT / 32;           // 32
constexpr int TPB   = 512;                // 8 waves per block
constexpr int GRID_MAIN  = 16 * 4 * TSN;  // 256 = 1 block/CU

__device__ inline unsigned short f2bf(float x) {      // round-to-nearest-even
    unsigned u = __float_as_uint(x);
    unsigned r = u + 0x7fff + ((u >> 16) & 1);
    return (unsigned short)(r >> 16);
}
__device__ inline float bf2f(unsigned short h) {
    return __uint_as_float(((unsigned)h) << 16);
}
__device__ inline unsigned pack2(unsigned short a, unsigned short b) {
    return (unsigned)a | ((unsigned)b << 16);
}

__global__ __launch_bounds__(TPB, 2) void chamfer_fused(
    const float* __restrict__ X, const float* __restrict__ Y,
    float* __restrict__ minq, unsigned* __restrict__ counter,
    float* __restrict__ out)
{
    __shared__ char  BL[TGT * 32];        // 32 KB
    __shared__ float wsum[8];
    __shared__ int   fireFlag;

    const int bid  = blockIdx.x;
    const int ts   = bid & 3;
    const int qg   = (bid >> 2) & 3;
    const int pair = bid >> 4;            // dir*8 + b
    const int dir  = pair >> 3, b = pair & 7;
    const int tid  = threadIdx.x;
    const int lane = tid & 63, wv = tid >> 6;          // wv: 0..7
    const int c    = lane & 31, h = lane >> 5;

    const float* __restrict__ Qraw = (dir ? Y : X) + b * 3 * NPTS;
    const float* __restrict__ Traw = (dir ? X : Y) + b * 3 * NPTS;

    // ---- pack this block's 1024-target slice into LDS (2 pts/thread) ----
    #pragma unroll
    for (int k = 0; k < 2; ++k) {
        const int p = k * TPB + tid;                     // 0..1023
        const int i = ts * TGT + p;
        float tx = Traw[i], ty = Traw[NPTS + i], tz = Traw[2 * NPTS + i];
        float r  = fmaf(tx, tx, fmaf(ty, ty, tz * tz));
        unsigned short hx = f2bf(tx), lx = f2bf(tx - bf2f(hx));
        unsigned short hy = f2bf(ty), ly = f2bf(ty - bf2f(hy));
        unsigned short hz = f2bf(tz), lz = f2bf(tz - bf2f(hz));
        unsigned short hr = f2bf(r),  lr = f2bf(r  - bf2f(hr));
        unsigned w0 = pack2(hx, lx), w2 = pack2(hy, ly), w4 = pack2(hz, lz);
        unsigned w6 = pack2(hr, lr);
        uint4v lo = {w0, w0, w2, w2};                    // k0..7
        uint4v hi = {w4, w4, w6, 0u};                    // k8..15
        const int sw = (p >> 2) & 1;                     // half-swap swizzle
        *(uint4v*)(BL + p * 32 + ((0 ^ sw) << 4)) = lo;
        *(uint4v*)(BL + p * 32 + ((1 ^ sw) << 4)) = hi;
    }

    // ---- B fragments (queries): 4 strips of 32 per wave ----
    union Frag { uint4v u; short8 s; };
    Frag qfr[4];
    float ra[4];
    #pragma unroll
    for (int s = 0; s < 4; ++s) {
        const int q = qg * 1024 + wv * 128 + s * 32 + c;
        float qx = Qraw[q], qy = Qraw[NPTS + q], qz = Qraw[2 * NPTS + q];
        ra[s] = fmaf(qx, qx, fmaf(qy, qy, qz * qz));
        float mx = -2.f * qx, my = -2.f * qy, mz = -2.f * qz;
        unsigned short hx = f2bf(mx), lx = f2bf(mx - bf2f(hx));
        unsigned short hy = f2bf(my), ly = f2bf(my - bf2f(hy));
        unsigned short hz = f2bf(mz), lz = f2bf(mz - bf2f(hz));
        uint4v f0 = {pack2(hx, hx), pack2(lx, lx), pack2(hy, hy), pack2(ly, ly)};
        uint4v f1 = {pack2(hz, hz), pack2(lz, lz), 0x3F803F80u, 0u};
        Frag f; f.u = h ? f1 : f0;
        qfr[s] = f;
    }

    __syncthreads();                                     // targets staged

    // ---- main loop: 32 tiles of 32 targets, 2 tiles per iter (R18) ----
    f32x16 run[4];
    #pragma unroll
    for (int s = 0; s < 4; ++s)
        #pragma unroll
        for (int i = 0; i < 16; ++i) run[s][i] = 3.4e38f;
    f32x16 zacc;
    #pragma unroll
    for (int i = 0; i < 16; ++i) zacc[i] = 0.f;

    // A lane map (targets): row = lane&31, k = h*8+j; swizzled read.
    const char* base = BL + c * 32 + ((h ^ ((c >> 2) & 1)) << 4);

    short8 tf0 = *(const short8*)(base);
    short8 tf1 = *(const short8*)(base + 1024);
    for (int t = 0; t < TILES; t += 2) {
        const int t2 = (t + 2) & (TILES - 1);            // wrap: dummy tail
        const int t3 = (t + 3) & (TILES - 1);
        short8 nf0 = *(const short8*)(base + t2 * 1024);
        short8 nf1 = *(const short8*)(base + t3 * 1024);
        #pragma unroll
        for (int s = 0; s < 4; ++s) {
            // D[m=target][n=query]: col (lane) = query, regs = 16 targets.
            f32x16 dA = __builtin_amdgcn_mfma_f32_32x32x16_bf16(tf0, qfr[s].s, zacc, 0, 0, 0);
            f32x16 dB = __builtin_amdgcn_mfma_f32_32x32x16_bf16(tf1, qfr[s].s, zacc, 0, 0, 0);
            #pragma unroll
            for (int i = 0; i < 16; ++i)
                run[s][i] = fminf(run[s][i], fminf(dA[i], dB[i]));
        }
        tf0 = nf0; tf1 = nf1;
    }

    // ---- epilogue: fmin tree over 16 regs + one h-half swap ----
    #pragma unroll
    for (int s = 0; s < 4; ++s) {
        float m0 = fminf(fminf(run[s][0],  run[s][1]),  fminf(run[s][2],  run[s][3]));
        float m1 = fminf(fminf(run[s][4],  run[s][5]),  fminf(run[s][6],  run[s][7]));
        float m2 = fminf(fminf(run[s][8],  run[s][9]),  fminf(run[s][10], run[s][11]));
        float m3 = fminf(fminf(run[s][12], run[s][13]), fminf(run[s][14], run[s][15]));
        float m  = fminf(fminf(m0, m1), fminf(m2, m3));
        m = fminf(m, __shfl_xor(m, 32));                 // combine h halves
        m += ra[s];                                      // ra + slice-min
        if (h == 0)
            minq[(size_t)ts * NQ + pair * 4096 + qg * 1024 + wv * 128 + s * 32 + c] = m;
    }

    // ---- last-block handshake (poison-proof) + fused final reduction ----
    __threadfence();                      // release own minq stores (all thr)
    __syncthreads();                      // all fences done before the atomic
    if (tid == 0) {
        unsigned old = atomicAdd(counter, 1u);           // device-scope
        fireFlag = ((old & 255u) == 255u);               // fires once/call
    }
    __syncthreads();

    if (fireFlag) {                        // block-uniform branch
        __threadfence();                   // acquire all blocks' minq
        const float4* mq4 = (const float4*)minq;
        float acc = 0.0f;
        #pragma unroll
        for (int k = 0; k < NQ / 4 / TPB; ++k) {         // 32 slots/thread
            const int idx = k * TPB + tid;
            float4 m = mq4[idx];
            #pragma unroll
            for (int s = 1; s < TSN; ++s) {
                float4 v = mq4[s * (NQ / 4) + idx];
                m.x = fminf(m.x, v.x); m.y = fminf(m.y, v.y);
                m.z = fminf(m.z, v.z); m.w = fminf(m.w, v.w);
            }
            acc += (m.x + m.y) + (m.z + m.w);
        }
        #pragma unroll
        for (int off = 1; off < 64; off <<= 1) acc += __shfl_xor(acc, off);
        if (lane == 0) wsum[wv] = acc;
        __syncthreads();
        if (tid == 0) {
            float tsum = ((wsum[0] + wsum[1]) + (wsum[2] + wsum[3]))
                       + ((wsum[4] + wsum[5]) + (wsum[6] + wsum[7]));
            out[0] = tsum * (1.0f / 65536.0f);           // mean of (d1+d2)/2
        }
    }
}

extern "C" void kernel_launch(void* const* d_in, const int* in_sizes, int n_in,
                              void* d_out, int out_size, void* d_ws, size_t ws_size,
                              hipStream_t stream) {
    const float* X = (const float*)d_in[0];
    const float* Y = (const float*)d_in[1];

    float*    minq    = (float*)d_ws;                        // 4*65536 f32 = 1 MB
    unsigned* counter = (unsigned*)(minq + (size_t)TSN * NQ);// 1 u32 (any init OK)
    float*    out     = (float*)d_out;

    chamfer_fused<<<GRID_MAIN, TPB, 0, stream>>>(X, Y, minq, counter, out);
}

// Round 21
// 19.716 us; speedup vs baseline: 3.4069x; 3.1759x over previous
//
#include <hip/hip_runtime.h>

// Chamfer loss via 32x32x16 MFMA. X, Y f32 [8, 3, 4096] -> scalar.
// dir 0: queries = X, targets = Y; dir 1: queries = Y, targets = X.
//
// d'(q,t) = ||t||^2 - 2 q.t with hi/lo-split bf16 (verified R6-R20):
//   k0..11: per coord: Q=(qh,qh,ql,ql) (qh+ql ~= -2q_c), T=(th,tl,th,tl)
//   k12,13: Q=(1,1), T=(rt_hi,rt_lo); k14,15 = 0.  K=16 exact.
// Swapped operands (R12): D = mfma(A=targets, B=queries) -> col = query =
// lane-local; 16 regs = 16 targets; epilogue = fmin tree + 1 shfl_xor(32).
//
// R21 = R18 VERBATIM (best: 19.75us, absmax 0). R19/R20 both spilled the
// accumulators (VGPR 100/84 < ~150 live) because the fused last-block
// reduce tail perturbs function-wide regalloc (rule #19) — the 2-kernel
// split is structurally necessary here. Do not add code to chamfer_main.
// Geometry: grid 256 = 16 pairs x 4 qgroups x 4 slices, 512 thr (8 waves,
// 2/SIMD), 32 KB LDS, half-swap swizzle.
// reduce: 64 blocks min over 4 slices + sum; poison-proof handshake.

typedef __attribute__((ext_vector_type(8))) short short8;
typedef __attribute__((ext_vector_type(16))) float f32x16;
typedef __attribute__((ext_vector_type(4))) unsigned uint4v;

constexpr int NPTS  = 4096;
constexpr int NB    = 8;
constexpr int NQ    = 2 * NB * NPTS;      // 65536 query slots
constexpr int TSN   = 4;                  // target slices
constexpr int TGT   = 1024;               // targets per slice
constexpr int TILES = TGT / 32;           // 32
constexpr int TPB   = 512;                // 8 waves per block
constexpr int GRID_MAIN  = 16 * 4 * TSN;  // 256 = 1 block/CU
constexpr int RED_BLOCKS = 64;

__device__ inline unsigned short f2bf(float x) {      // round-to-nearest-even
    unsigned u = __float_as_uint(x);
    unsigned r = u + 0x7fff + ((u >> 16) & 1);
    return (unsigned short)(r >> 16);
}
__device__ inline float bf2f(unsigned short h) {
    return __uint_as_float(((unsigned)h) << 16);
}
__device__ inline unsigned pack2(unsigned short a, unsigned short b) {
    return (unsigned)a | ((unsigned)b << 16);
}

__global__ __launch_bounds__(TPB, 2) void chamfer_main(
    const float* __restrict__ X, const float* __restrict__ Y,
    float* __restrict__ minq)
{
    __shared__ char BL[TGT * 32];         // 32 KB

    const int bid  = blockIdx.x;
    const int ts   = bid & 3;
    const int qg   = (bid >> 2) & 3;
    const int pair = bid >> 4;            // dir*8 + b
    const int dir  = pair >> 3, b = pair & 7;
    const int tid  = threadIdx.x;
    const int lane = tid & 63, wv = tid >> 6;          // wv: 0..7
    const int c    = lane & 31, h = lane >> 5;

    const float* __restrict__ Qraw = (dir ? Y : X) + b * 3 * NPTS;
    const float* __restrict__ Traw = (dir ? X : Y) + b * 3 * NPTS;

    // ---- pack this block's 1024-target slice into LDS (2 pts/thread) ----
    #pragma unroll
    for (int k = 0; k < 2; ++k) {
        const int p = k * TPB + tid;                     // 0..1023
        const int i = ts * TGT + p;
        float tx = Traw[i], ty = Traw[NPTS + i], tz = Traw[2 * NPTS + i];
        float r  = fmaf(tx, tx, fmaf(ty, ty, tz * tz));
        unsigned short hx = f2bf(tx), lx = f2bf(tx - bf2f(hx));
        unsigned short hy = f2bf(ty), ly = f2bf(ty - bf2f(hy));
        unsigned short hz = f2bf(tz), lz = f2bf(tz - bf2f(hz));
        unsigned short hr = f2bf(r),  lr = f2bf(r  - bf2f(hr));
        unsigned w0 = pack2(hx, lx), w2 = pack2(hy, ly), w4 = pack2(hz, lz);
        unsigned w6 = pack2(hr, lr);
        uint4v lo = {w0, w0, w2, w2};                    // k0..7
        uint4v hi = {w4, w4, w6, 0u};                    // k8..15
        const int sw = (p >> 2) & 1;                     // half-swap swizzle
        *(uint4v*)(BL + p * 32 + ((0 ^ sw) << 4)) = lo;
        *(uint4v*)(BL + p * 32 + ((1 ^ sw) << 4)) = hi;
    }

    // ---- B fragments (queries): 4 strips of 32 per wave ----
    union Frag { uint4v u; short8 s; };
    Frag qfr[4];
    float ra[4];
    #pragma unroll
    for (int s = 0; s < 4; ++s) {
        const int q = qg * 1024 + wv * 128 + s * 32 + c;
        float qx = Qraw[q], qy = Qraw[NPTS + q], qz = Qraw[2 * NPTS + q];
        ra[s] = fmaf(qx, qx, fmaf(qy, qy, qz * qz));
        float mx = -2.f * qx, my = -2.f * qy, mz = -2.f * qz;
        unsigned short hx = f2bf(mx), lx = f2bf(mx - bf2f(hx));
        unsigned short hy = f2bf(my), ly = f2bf(my - bf2f(hy));
        unsigned short hz = f2bf(mz), lz = f2bf(mz - bf2f(hz));
        uint4v f0 = {pack2(hx, hx), pack2(lx, lx), pack2(hy, hy), pack2(ly, ly)};
        uint4v f1 = {pack2(hz, hz), pack2(lz, lz), 0x3F803F80u, 0u};
        Frag f; f.u = h ? f1 : f0;
        qfr[s] = f;
    }

    __syncthreads();                                     // targets staged

    // ---- main loop: 32 tiles of 32 targets, 2 tiles per iter ----
    f32x16 run[4];
    #pragma unroll
    for (int s = 0; s < 4; ++s)
        #pragma unroll
        for (int i = 0; i < 16; ++i) run[s][i] = 3.4e38f;
    f32x16 zacc;
    #pragma unroll
    for (int i = 0; i < 16; ++i) zacc[i] = 0.f;

    // A lane map (targets): row = lane&31, k = h*8+j; swizzled read.
    const char* base = BL + c * 32 + ((h ^ ((c >> 2) & 1)) << 4);

    short8 tf0 = *(const short8*)(base);
    short8 tf1 = *(const short8*)(base + 1024);
    for (int t = 0; t < TILES; t += 2) {
        const int t2 = (t + 2) & (TILES - 1);            // wrap: dummy tail
        const int t3 = (t + 3) & (TILES - 1);
        short8 nf0 = *(const short8*)(base + t2 * 1024);
        short8 nf1 = *(const short8*)(base + t3 * 1024);
        #pragma unroll
        for (int s = 0; s < 4; ++s) {
            // D[m=target][n=query]: col (lane) = query, regs = 16 targets.
            f32x16 dA = __builtin_amdgcn_mfma_f32_32x32x16_bf16(tf0, qfr[s].s, zacc, 0, 0, 0);
            f32x16 dB = __builtin_amdgcn_mfma_f32_32x32x16_bf16(tf1, qfr[s].s, zacc, 0, 0, 0);
            #pragma unroll
            for (int i = 0; i < 16; ++i)
                run[s][i] = fminf(run[s][i], fminf(dA[i], dB[i]));
        }
        tf0 = nf0; tf1 = nf1;
    }

    // ---- epilogue: fmin tree over 16 regs + one h-half swap ----
    #pragma unroll
    for (int s = 0; s < 4; ++s) {
        float m0 = fminf(fminf(run[s][0],  run[s][1]),  fminf(run[s][2],  run[s][3]));
        float m1 = fminf(fminf(run[s][4],  run[s][5]),  fminf(run[s][6],  run[s][7]));
        float m2 = fminf(fminf(run[s][8],  run[s][9]),  fminf(run[s][10], run[s][11]));
        float m3 = fminf(fminf(run[s][12], run[s][13]), fminf(run[s][14], run[s][15]));
        float m  = fminf(fminf(m0, m1), fminf(m2, m3));
        m = fminf(m, __shfl_xor(m, 32));                 // combine h halves
        m += ra[s];                                      // ra + slice-min
        if (h == 0)
            minq[(size_t)ts * NQ + pair * 4096 + qg * 1024 + wv * 128 + s * 32 + c] = m;
    }
}

__global__ __launch_bounds__(256) void chamfer_reduce(
    const float4* __restrict__ mq4, float* __restrict__ partials,
    unsigned* __restrict__ counter, float* __restrict__ out)
{
    __shared__ float wsum[4];
    __shared__ int   fireFlag;
    const int tid = threadIdx.x;
    const int lane = tid & 63, wv = tid >> 6;
    const int idx = blockIdx.x * 256 + tid;              // 0..16383 float4 slots

    float4 m = mq4[idx];
    #pragma unroll
    for (int s = 1; s < TSN; ++s) {
        float4 v = mq4[(size_t)s * (NQ / 4) + idx];
        m.x = fminf(m.x, v.x); m.y = fminf(m.y, v.y);
        m.z = fminf(m.z, v.z); m.w = fminf(m.w, v.w);
    }
    float v = (m.x + m.y) + (m.z + m.w);
    #pragma unroll
    for (int off = 1; off < 64; off <<= 1) v += __shfl_xor(v, off);
    if (lane == 0) wsum[wv] = v;
    __syncthreads();
    if (tid == 0) {
        partials[blockIdx.x] = (wsum[0] + wsum[1]) + (wsum[2] + wsum[3]);
        __threadfence();                                 // publish partial
        unsigned old = atomicAdd(counter, 1u);           // device-scope
        fireFlag = ((old & 63u) == 63u);                 // poison-proof
    }
    __syncthreads();

    if (fireFlag) {
        __threadfence();                                 // acquire partials
        if (tid < 64) {
            float p = partials[tid];                     // exactly 64 partials
            #pragma unroll
            for (int off = 1; off < 64; off <<= 1) p += __shfl_xor(p, off);
            if (tid == 0)
                out[0] = p * (1.0f / 65536.0f);          // mean of (d1+d2)/2
        }
    }
}

extern "C" void kernel_launch(void* const* d_in, const int* in_sizes, int n_in,
                              void* d_out, int out_size, void* d_ws, size_t ws_size,
                              hipStream_t stream) {
    const float* X = (const float*)d_in[0];
    const float* Y = (const float*)d_in[1];

    float*    minq     = (float*)d_ws;                         // 4*65536 f32 = 1 MB
    float*    partials = minq + (size_t)TSN * NQ;              // 64 f32
    unsigned* counter  = (unsigned*)(partials + RED_BLOCKS);   // 1 u32 (any init OK)
    float*    out      = (float*)d_out;

    chamfer_main<<<GRID_MAIN, TPB, 0, stream>>>(X, Y, minq);
    chamfer_reduce<<<RED_BLOCKS, 256, 0, stream>>>(
        (const float4*)minq, partials, counter, out);
}